// Round 6
// baseline (507.829 us; speedup 1.0000x reference)
//
#include <hip/hip_runtime.h>
#include <hip/hip_bf16.h>
#include <math.h>

// Problem constants (fixed by the reference)
#define HEADS 32
#define DIM_HEAD 64
#define DM 2048          // HEADS * DIM_HEAD
#define BATCH 2
#define SEQ 1024
#define NROWS (BATCH * SEQ)      // 2048 rows of DM
#define NVEC (NROWS * HEADS)     // 65536 per-head vectors
#define N_GROUPS 22
#define N_LEVELS 8
#define EPS_NORM 1e-8f
#define EPS_RMS 1e-6f

typedef float f32x4 __attribute__((ext_vector_type(4)));
typedef __bf16 bf16x8 __attribute__((ext_vector_type(8)));
typedef unsigned short u16x8 __attribute__((ext_vector_type(8)));
typedef unsigned short u16x4 __attribute__((ext_vector_type(4)));

__device__ __forceinline__ unsigned short f2bf(float x) {
  union { float f; unsigned u; } v; v.f = x;
  unsigned r = v.u + 0x7fffu + ((v.u >> 16) & 1u);  // RTN-even
  return (unsigned short)(r >> 16);
}
__device__ __forceinline__ float bf2f(unsigned short h) {
  union { unsigned u; float f; } v; v.u = ((unsigned)h) << 16;
  return v.f;
}
__device__ __forceinline__ bf16x8 ldfrag(const unsigned short* p) {
  return __builtin_bit_cast(bf16x8, *(const u16x8*)p);
}
#define MFMA16(a, b, c) __builtin_amdgcn_mfma_f32_16x16x32_bf16((a), (b), (c), 0, 0, 0)

__device__ __forceinline__ void stage16(const unsigned short* g, unsigned short* lds) {
  __builtin_amdgcn_global_load_lds(
      (const __attribute__((address_space(1))) unsigned int*)g,
      (__attribute__((address_space(3))) unsigned int*)lds, 16, 0, 0);
}

// ---------------------------------------------------------------------------
// fp32 -> bf16 hi/lo split (lo optional), 8 elements/thread
// ---------------------------------------------------------------------------
__global__ __launch_bounds__(256) void split_convert_kernel(
    const float* __restrict__ X, unsigned short* __restrict__ hi,
    unsigned short* __restrict__ lo, int n8) {
  const int i = blockIdx.x * 256 + threadIdx.x;
  if (i >= n8) return;
  const float4 a = ((const float4*)X)[2 * i];
  const float4 b = ((const float4*)X)[2 * i + 1];
  const float v[8] = {a.x, a.y, a.z, a.w, b.x, b.y, b.z, b.w};
  u16x8 h, l;
#pragma unroll
  for (int j = 0; j < 8; ++j) {
    const unsigned short hh = f2bf(v[j]);
    h[j] = hh;
    l[j] = f2bf(v[j] - bf2f(hh));
  }
  ((u16x8*)hi)[i] = h;
  if (lo) ((u16x8*)lo)[i] = l;
}

// ---------------------------------------------------------------------------
// Batched weight transpose+split: W [K][M] fp32 -> T [M][K] bf16 hi(/lo).
// grid (M/64, K/64, 4): z selects {Wq, Wk, Wv, Wo}.
// ---------------------------------------------------------------------------
__global__ __launch_bounds__(256) void transpose_split_batch_kernel(
    const float* __restrict__ W0, const float* __restrict__ W1,
    const float* __restrict__ W2, const float* __restrict__ W3,
    unsigned short* __restrict__ T0h, unsigned short* __restrict__ T1h,
    unsigned short* __restrict__ T1l, unsigned short* __restrict__ T2h,
    unsigned short* __restrict__ T2l, unsigned short* __restrict__ T3h) {
  const int z = blockIdx.z;
  const float* W = (z == 0) ? W0 : (z == 1) ? W1 : (z == 2) ? W2 : W3;
  unsigned short* Th = (z == 0) ? T0h : (z == 1) ? T1h : (z == 2) ? T2h : T3h;
  unsigned short* Tl = (z == 1) ? T1l : (z == 2) ? T2l : nullptr;

  __shared__ float S[64][65];
  const int t = threadIdx.x;
  const int tk = blockIdx.y * 64, tm = blockIdx.x * 64;
  {
    const int r = t >> 2, cs = (t & 3) * 16;
    const float* src = W + (size_t)(tk + r) * DM + tm + cs;
#pragma unroll
    for (int j = 0; j < 16; j += 4) {
      float4 v = *(const float4*)(src + j);
      S[r][cs + j] = v.x; S[r][cs + j + 1] = v.y;
      S[r][cs + j + 2] = v.z; S[r][cs + j + 3] = v.w;
    }
  }
  __syncthreads();
  const int m = t >> 2, ks = (t & 3) * 16;
  u16x8 h0, h1, l0, l1;
#pragma unroll
  for (int j = 0; j < 8; ++j) {
    const float v = S[ks + j][m];
    const unsigned short hh = f2bf(v);
    h0[j] = hh; l0[j] = f2bf(v - bf2f(hh));
  }
#pragma unroll
  for (int j = 0; j < 8; ++j) {
    const float v = S[ks + 8 + j][m];
    const unsigned short hh = f2bf(v);
    h1[j] = hh; l1[j] = f2bf(v - bf2f(hh));
  }
  const size_t o = (size_t)(tm + m) * DM + tk + ks;
  *(u16x8*)&Th[o] = h0; *(u16x8*)&Th[o + 8] = h1;
  if (Tl) { *(u16x8*)&Tl[o] = l0; *(u16x8*)&Tl[o + 8] = l1; }
}

// ---------------------------------------------------------------------------
// Fused QKV GEMM: A[N=2048][K=2048] @ Bcat[M=6144][K]^T.
// Segments: 0..2047 Wq^T (plain), 2048..4095 Wk^T, 4096..6143 Wv^T (split).
// ---------------------------------------------------------------------------
__global__ __launch_bounds__(256) void qkv_gemm_kernel(
    const unsigned short* __restrict__ Ahi, const unsigned short* __restrict__ Alo,
    const unsigned short* __restrict__ Bhi, const unsigned short* __restrict__ Blo,
    float* __restrict__ q, float* __restrict__ k, float* __restrict__ v) {
  __shared__ unsigned short lAhi[128 * 32];
  __shared__ unsigned short lBhi[128 * 32];
  __shared__ unsigned short lAlo[128 * 32];
  __shared__ unsigned short lBlo[128 * 32];

  const int t = threadIdx.x;
  const int lane = t & 63, wave = t >> 6;
  const int wr = wave >> 1, wc = wave & 1;
  const int gm0 = blockIdx.y * 128;
  const int gnc = blockIdx.x * 128;
  const int seg = gnc >> 11;
  const bool split = (seg != 0);
  const int lrsub = lane >> 2;
  const int lcsub = lane & 3;

  f32x4 acc[4][4] = {};

  for (int kt = 0; kt < DM; kt += 32) {
    __syncthreads();
#pragma unroll
    for (int rg = wave; rg < 8; rg += 4) {
      const int lrow = rg * 16 + lrsub;
      const int c = lcsub ^ ((lrow >> 1) & 3);
      const size_t goffA = (size_t)(gm0 + lrow) * DM + kt + c * 8;
      const size_t goffB = (size_t)(gnc + lrow) * DM + kt + c * 8;
      stage16(Ahi + goffA, lAhi + rg * 512);
      stage16(Bhi + goffB, lBhi + rg * 512);
      if (split) {
        stage16(Alo + goffA, lAlo + rg * 512);
        stage16(Blo + goffB, lBlo + rg * 512);
      }
    }
    __syncthreads();

    bf16x8 ah[4], bh[4], al[4], bl[4];
#pragma unroll
    for (int i = 0; i < 4; ++i) {
      const int mrow = wr * 64 + i * 16 + (lane & 15);
      const int offa = mrow * 32 + (((lane >> 4) ^ ((mrow >> 1) & 3)) << 3);
      ah[i] = ldfrag(&lAhi[offa]);
      const int nrow = wc * 64 + i * 16 + (lane & 15);
      const int offb = nrow * 32 + (((lane >> 4) ^ ((nrow >> 1) & 3)) << 3);
      bh[i] = ldfrag(&lBhi[offb]);
      if (split) {
        al[i] = ldfrag(&lAlo[offa]);
        bl[i] = ldfrag(&lBlo[offb]);
      }
    }
#pragma unroll
    for (int i = 0; i < 4; ++i)
#pragma unroll
      for (int j = 0; j < 4; ++j) {
        acc[i][j] = MFMA16(ah[i], bh[j], acc[i][j]);
        if (split) {
          acc[i][j] = MFMA16(ah[i], bl[j], acc[i][j]);
          acc[i][j] = MFMA16(al[i], bh[j], acc[i][j]);
        }
      }
  }

  float* C = (seg == 0) ? q : (seg == 1) ? k : v;
  const int gn0 = gnc & 2047;
#pragma unroll
  for (int i = 0; i < 4; ++i) {
    const int row = gm0 + wr * 64 + i * 16 + ((lane >> 4) << 2);
#pragma unroll
    for (int j = 0; j < 4; ++j) {
      const int col = gn0 + wc * 64 + j * 16 + (lane & 15);
#pragma unroll
      for (int r = 0; r < 4; ++r)
        C[(size_t)(row + r) * DM + col] = acc[i][j][r];
    }
  }
}

// ---------------------------------------------------------------------------
// Output projection, split-K=2 (plain bf16), partials into Cpart.
// ---------------------------------------------------------------------------
__global__ __launch_bounds__(256) void gemm_out_splitk_kernel(
    const unsigned short* __restrict__ Ahi, const unsigned short* __restrict__ Bt,
    float* __restrict__ Cpart) {
  __shared__ unsigned short lAhi[128 * 32];
  __shared__ unsigned short lBhi[128 * 32];

  const int t = threadIdx.x;
  const int lane = t & 63, wave = t >> 6;
  const int wr = wave >> 1, wc = wave & 1;
  const int gm0 = blockIdx.y * 128, gn0 = blockIdx.x * 128;
  const int z = blockIdx.z;
  const int k0 = z * (DM / 2);
  const int lrsub = lane >> 2;
  const int lcsub = lane & 3;

  f32x4 acc[4][4] = {};

  for (int kt = k0; kt < k0 + DM / 2; kt += 32) {
    __syncthreads();
#pragma unroll
    for (int rg = wave; rg < 8; rg += 4) {
      const int lrow = rg * 16 + lrsub;
      const int c = lcsub ^ ((lrow >> 1) & 3);
      stage16(Ahi + (size_t)(gm0 + lrow) * DM + kt + c * 8, lAhi + rg * 512);
      stage16(Bt + (size_t)(gn0 + lrow) * DM + kt + c * 8, lBhi + rg * 512);
    }
    __syncthreads();

    bf16x8 ah[4], bh[4];
#pragma unroll
    for (int i = 0; i < 4; ++i) {
      const int mrow = wr * 64 + i * 16 + (lane & 15);
      ah[i] = ldfrag(&lAhi[mrow * 32 + (((lane >> 4) ^ ((mrow >> 1) & 3)) << 3)]);
      const int nrow = wc * 64 + i * 16 + (lane & 15);
      bh[i] = ldfrag(&lBhi[nrow * 32 + (((lane >> 4) ^ ((nrow >> 1) & 3)) << 3)]);
    }
#pragma unroll
    for (int i = 0; i < 4; ++i)
#pragma unroll
      for (int j = 0; j < 4; ++j)
        acc[i][j] = MFMA16(ah[i], bh[j], acc[i][j]);
  }

  float* C = Cpart + (size_t)z * NROWS * DM;
#pragma unroll
  for (int i = 0; i < 4; ++i) {
    const int row = gm0 + wr * 64 + i * 16 + ((lane >> 4) << 2);
#pragma unroll
    for (int j = 0; j < 4; ++j) {
      const int col = gn0 + wc * 64 + j * 16 + (lane & 15);
#pragma unroll
      for (int r = 0; r < 4; ++r)
        C[(size_t)(row + r) * DM + col] = acc[i][j][r];
    }
  }
}

__global__ __launch_bounds__(256) void add2_f4_kernel(
    const float* __restrict__ a, const float* __restrict__ b,
    float* __restrict__ o, int n4) {
  const int i = blockIdx.x * 256 + threadIdx.x;
  if (i >= n4) return;
  const float4 x = ((const float4*)a)[i];
  const float4 y = ((const float4*)b)[i];
  ((float4*)o)[i] = make_float4(x.x + y.x, x.y + y.y, x.z + y.z, x.w + y.w);
}

// ---------------------------------------------------------------------------
// Wave reductions
// ---------------------------------------------------------------------------
__device__ __forceinline__ float wave_sum(float x) {
#pragma unroll
  for (int o = 32; o > 0; o >>= 1) x += __shfl_xor(x, o, 64);
  return x;
}

// ---------------------------------------------------------------------------
// RMSNorm in place (fp32), one block per row.  (k path)
// ---------------------------------------------------------------------------
__global__ __launch_bounds__(256) void rmsnorm_kernel(
    float* __restrict__ y, const float* __restrict__ w) {
  __shared__ float rbuf[4];
  const int row = blockIdx.x;
  float* p = y + (size_t)row * DM;
  const int t = threadIdx.x;
  const int wave = t >> 6, lane = t & 63;

  float ss = 0.f;
#pragma unroll
  for (int c = t; c < DM; c += 256) { float v = p[c]; ss += v * v; }
  ss = wave_sum(ss);
  if (lane == 0) rbuf[wave] = ss;
  __syncthreads();
  ss = rbuf[0] + rbuf[1] + rbuf[2] + rbuf[3];
  const float scale = rsqrtf(ss * (1.0f / DM) + EPS_RMS);
#pragma unroll
  for (int c = t; c < DM; c += 256) p[c] = p[c] * scale * w[c];
}

// ---------------------------------------------------------------------------
// RMSNorm -> bf16 hi/lo with extra post-scale (q path: folds 1/8)
// ---------------------------------------------------------------------------
__global__ __launch_bounds__(256) void rmsnorm_split_kernel(
    const float* __restrict__ y, const float* __restrict__ w,
    unsigned short* __restrict__ hi, unsigned short* __restrict__ lo,
    float post) {
  __shared__ float rbuf[4];
  const int row = blockIdx.x;
  const float* p = y + (size_t)row * DM;
  const int t = threadIdx.x;
  const int wave = t >> 6, lane = t & 63;

  const int c0 = t * 8;
  float4 a = *(const float4*)(p + c0);
  float4 b = *(const float4*)(p + c0 + 4);
  float v[8] = {a.x, a.y, a.z, a.w, b.x, b.y, b.z, b.w};
  float ss = 0.f;
#pragma unroll
  for (int j = 0; j < 8; ++j) ss += v[j] * v[j];
  ss = wave_sum(ss);
  if (lane == 0) rbuf[wave] = ss;
  __syncthreads();
  ss = rbuf[0] + rbuf[1] + rbuf[2] + rbuf[3];
  const float scale = rsqrtf(ss * (1.0f / DM) + EPS_RMS) * post;

  u16x8 hv, lv;
#pragma unroll
  for (int j = 0; j < 8; ++j) {
    const float val = v[j] * scale * w[c0 + j];
    const unsigned short hh = f2bf(val);
    hv[j] = hh; lv[j] = f2bf(val - bf2f(hh));
  }
  *(u16x8*)&hi[(size_t)row * DM + c0] = hv;
  *(u16x8*)&lo[(size_t)row * DM + c0] = lv;
}

// ---------------------------------------------------------------------------
// RotorQuant roundtrip. WRITE_BF: emit bf16 hi/lo; else fp32 in place.
// ---------------------------------------------------------------------------
__device__ __forceinline__ float qnearest(float v, const float* __restrict__ C) {
  float best = C[0];
  float bd = fabsf(v - C[0]);
#pragma unroll
  for (int i = 1; i < N_LEVELS; ++i) {
    float d = fabsf(v - C[i]);
    if (d < bd) { bd = d; best = C[i]; }
  }
  return best;
}

template <bool WRITE_BF>
__global__ __launch_bounds__(256) void quant_kernel(
    float* __restrict__ kv, const float* __restrict__ M,
    const float* __restrict__ Mt, const float* __restrict__ C,
    unsigned short* __restrict__ hi, unsigned short* __restrict__ lo) {
  const int vec = blockIdx.x * blockDim.x + threadIdx.x;
  if (vec >= NVEC) return;
  float* p = kv + (size_t)vec * DIM_HEAD;

  float h[66];
  float ss = 0.f;
#pragma unroll
  for (int d = 0; d < DIM_HEAD; ++d) { h[d] = p[d]; ss += h[d] * h[d]; }
  float norm = fmaxf(sqrtf(ss), EPS_NORM);
  const float inv = 1.0f / norm;
#pragma unroll
  for (int d = 0; d < DIM_HEAD; ++d) h[d] *= inv;
  h[64] = 0.f; h[65] = 0.f;

#pragma unroll
  for (int g = 0; g < N_GROUPS; ++g) {
    const float* Mg  = M  + g * 9;
    const float* Mtg = Mt + g * 9;
    const float a0 = h[3 * g + 0], a1 = h[3 * g + 1], a2 = h[3 * g + 2];
    const float r0 = a0 * Mg[0] + a1 * Mg[3] + a2 * Mg[6];
    const float r1 = a0 * Mg[1] + a1 * Mg[4] + a2 * Mg[7];
    const float r2 = a0 * Mg[2] + a1 * Mg[5] + a2 * Mg[8];
    const float d0 = qnearest(r0, C);
    const float d1 = qnearest(r1, C);
    const float d2 = qnearest(r2, C);
    h[3 * g + 0] = d0 * Mtg[0] + d1 * Mtg[3] + d2 * Mtg[6];
    h[3 * g + 1] = d0 * Mtg[1] + d1 * Mtg[4] + d2 * Mtg[7];
    h[3 * g + 2] = d0 * Mtg[2] + d1 * Mtg[5] + d2 * Mtg[8];
  }
  if (WRITE_BF) {
#pragma unroll
    for (int g8 = 0; g8 < 8; ++g8) {
      u16x8 hv, lv;
#pragma unroll
      for (int j = 0; j < 8; ++j) {
        const float val = h[g8 * 8 + j] * norm;
        const unsigned short hh = f2bf(val);
        hv[j] = hh; lv[j] = f2bf(val - bf2f(hh));
      }
      *(u16x8*)&hi[(size_t)vec * DIM_HEAD + g8 * 8] = hv;
      *(u16x8*)&lo[(size_t)vec * DIM_HEAD + g8 * 8] = lv;
    }
  } else {
#pragma unroll
    for (int d = 0; d < DIM_HEAD; ++d) p[d] = h[d] * norm;
  }
}

// ---------------------------------------------------------------------------
// Per-head V transpose + split: v[b][s][h*64+d] fp32 -> vt[(bh*64+d)][s] hi/lo
// ---------------------------------------------------------------------------
__global__ __launch_bounds__(256) void vt_split_kernel(
    const float* __restrict__ v, unsigned short* __restrict__ hi,
    unsigned short* __restrict__ lo) {
  __shared__ float T[64][65];
  const int s0 = blockIdx.x * 64;
  const int bh = blockIdx.y;
  const int b = bh >> 5, h = bh & 31;
  const int t = threadIdx.x;
  {
    const int sr = t >> 2, dseg = (t & 3) * 16;
    const float* src = v + ((size_t)(b * SEQ + s0 + sr) * DM + h * 64 + dseg);
#pragma unroll
    for (int j = 0; j < 16; j += 4) {
      float4 a = *(const float4*)(src + j);
      T[sr][dseg + j] = a.x; T[sr][dseg + j + 1] = a.y;
      T[sr][dseg + j + 2] = a.z; T[sr][dseg + j + 3] = a.w;
    }
  }
  __syncthreads();
  const int d = t >> 2, sseg = (t & 3) * 16;
  u16x8 h0, h1, l0, l1;
#pragma unroll
  for (int j = 0; j < 8; ++j) {
    const float val = T[sseg + j][d];
    const unsigned short hh = f2bf(val);
    h0[j] = hh; l0[j] = f2bf(val - bf2f(hh));
  }
#pragma unroll
  for (int j = 0; j < 8; ++j) {
    const float val = T[sseg + 8 + j][d];
    const unsigned short hh = f2bf(val);
    h1[j] = hh; l1[j] = f2bf(val - bf2f(hh));
  }
  const size_t o = (size_t)(bh * 64 + d) * SEQ + s0 + sseg;
  *(u16x8*)&hi[o] = h0; *(u16x8*)&hi[o + 8] = h1;
  *(u16x8*)&lo[o] = l0; *(u16x8*)&lo[o + 8] = l1;
}

// ---------------------------------------------------------------------------
// MFMA flash attention, split-bf16. Block = (b,h,128 q rows), 256 threads.
// Wave w owns q rows [w*32, w*32+32) as 2 subtiles of 16. K-frag and Vt-frag
// LDS reads are shared across both subtiles; P-frag reads hoisted out of the
// mt loop. alpha / l broadcasts via shuffles (no LDS). LDS = exactly 64 KB.
// ---------------------------------------------------------------------------
__global__ __launch_bounds__(256) void attn_mfma_kernel(
    const unsigned short* __restrict__ qhi, const unsigned short* __restrict__ qlo,
    const unsigned short* __restrict__ khi, const unsigned short* __restrict__ klo,
    const unsigned short* __restrict__ vthi, const unsigned short* __restrict__ vtlo,
    unsigned short* __restrict__ ohi) {
  __shared__ unsigned short Ks_h[4096], Ks_l[4096];   // [64 key][64 d]
  __shared__ unsigned short Vt_h[4096], Vt_l[4096];   // [64 d][64 s]
  __shared__ unsigned short Ps_h[8192], Ps_l[8192];   // [128 q][64 key]

  const int qt = blockIdx.x;        // 0..7 (128-row q tiles)
  const int bh = blockIdx.y;        // 0..63
  const int h = bh & 31, b = bh >> 5;
  const int q0 = qt * 128;
  const int t = threadIdx.x, lane = t & 63, w = t >> 6;
  const int quad = lane >> 4, l15 = lane & 15;
  const int srow = lane >> 3, schunk = lane & 7;

  // wave w stages rows [rowbase, rowbase+8*its) of a [*][64 u16] tile
  auto stage = [&](const unsigned short* g, int stride, unsigned short* arr,
                   int rowbase, int its) {
    for (int it = 0; it < its; ++it) {
      const int r = rowbase + it * 8 + srow;
      const int c = schunk ^ (r & 7);
      stage16(g + (size_t)r * stride + c * 8, arr + (rowbase + it * 8) * 64);
    }
  };

  // ---- Q preload (staged via Ps buffers): rows w*32 .. w*32+31
  stage(qhi + ((size_t)(b * SEQ + q0) * DM + h * 64), DM, Ps_h, w * 32, 4);
  stage(qlo + ((size_t)(b * SEQ + q0) * DM + h * 64), DM, Ps_l, w * 32, 4);
  __syncthreads();
  bf16x8 qh[2][2], ql[2][2];
#pragma unroll
  for (int qs = 0; qs < 2; ++qs)
#pragma unroll
    for (int ks = 0; ks < 2; ++ks) {
      const int row = w * 32 + qs * 16 + l15;
      const int off = row * 64 + (((quad + 4 * ks) ^ (row & 7)) << 3);
      qh[qs][ks] = ldfrag(&Ps_h[off]);
      ql[qs][ks] = ldfrag(&Ps_l[off]);
    }

  f32x4 acc[2][4] = {};     // [qs][mt]: O^T rows d=mt*16+quad*4+r, col q
  float m_prev[2][4] = {{-INFINITY, -INFINITY, -INFINITY, -INFINITY},
                        {-INFINITY, -INFINITY, -INFINITY, -INFINITY}};
  float lsum[2][4] = {{0.f, 0.f, 0.f, 0.f}, {0.f, 0.f, 0.f, 0.f}};

  const unsigned short* gkh = khi + ((size_t)(b * SEQ) * DM + h * 64);
  const unsigned short* gkl = klo + ((size_t)(b * SEQ) * DM + h * 64);
  const unsigned short* gvh = vthi + (size_t)(bh * 64) * SEQ;
  const unsigned short* gvl = vtlo + (size_t)(bh * 64) * SEQ;

  for (int kt = 0; kt < SEQ; kt += 64) {
    __syncthreads();                       // prev iter's K/Vt frag reads done
    stage(gkh + (size_t)kt * DM, DM, Ks_h, w * 16, 2);
    stage(gkl + (size_t)kt * DM, DM, Ks_l, w * 16, 2);
    stage(gvh + kt, SEQ, Vt_h, w * 16, 2);
    stage(gvl + kt, SEQ, Vt_l, w * 16, 2);
    __syncthreads();                       // staging drained

    // ---- S = (Q/8) @ K^T; K frags shared across both q-subtiles
    f32x4 s[2][4] = {};
#pragma unroll
    for (int nt = 0; nt < 4; ++nt) {
      bf16x8 kh[2], kl[2];
#pragma unroll
      for (int ks = 0; ks < 2; ++ks) {
        const int row = nt * 16 + l15;
        const int off = row * 64 + (((quad + 4 * ks) ^ (row & 7)) << 3);
        kh[ks] = ldfrag(&Ks_h[off]);
        kl[ks] = ldfrag(&Ks_l[off]);
      }
#pragma unroll
      for (int qs = 0; qs < 2; ++qs)
#pragma unroll
        for (int ks = 0; ks < 2; ++ks) {
          s[qs][nt] = MFMA16(qh[qs][ks], kh[ks], s[qs][nt]);
          s[qs][nt] = MFMA16(qh[qs][ks], kl[ks], s[qs][nt]);
          s[qs][nt] = MFMA16(ql[qs][ks], kh[ks], s[qs][nt]);
        }
    }

    // ---- online softmax per q row; alpha broadcast via shuffle
    float alph[2];
#pragma unroll
    for (int qs = 0; qs < 2; ++qs) {
      float asave[4];
#pragma unroll
      for (int r = 0; r < 4; ++r) {
        float mx = fmaxf(fmaxf(s[qs][0][r], s[qs][1][r]),
                         fmaxf(s[qs][2][r], s[qs][3][r]));
#pragma unroll
        for (int off = 1; off < 16; off <<= 1) mx = fmaxf(mx, __shfl_xor(mx, off, 64));
        const float mn = fmaxf(m_prev[qs][r], mx);
        const float al = __expf(m_prev[qs][r] - mn);
        float rs = 0.f;
#pragma unroll
        for (int nt = 0; nt < 4; ++nt) {
          const float e = __expf(s[qs][nt][r] - mn);
          s[qs][nt][r] = e; rs += e;
        }
#pragma unroll
        for (int off = 1; off < 16; off <<= 1) rs += __shfl_xor(rs, off, 64);
        lsum[qs][r] = lsum[qs][r] * al + rs;
        m_prev[qs][r] = mn;
        asave[r] = al;
        // P row write (wave-private rows): split to bf16 hi/lo
        const int prow = w * 32 + qs * 16 + quad * 4 + r;
#pragma unroll
        for (int nt = 0; nt < 4; ++nt) {
          const int kk = nt * 16 + l15;
          const int off2 = prow * 64 + (((kk >> 3) ^ (prow & 7)) << 3) + (kk & 7);
          const unsigned short hh = f2bf(s[qs][nt][r]);
          Ps_h[off2] = hh;
          Ps_l[off2] = f2bf(s[qs][nt][r] - bf2f(hh));
        }
      }
      // broadcast alpha[q=l15] to all lanes: src quad = l15>>2, reg = l15&3
      const int src = (l15 >> 2) << 4;
      const float a0 = __shfl(asave[0], src, 64);
      const float a1 = __shfl(asave[1], src, 64);
      const float a2 = __shfl(asave[2], src, 64);
      const float a3 = __shfl(asave[3], src, 64);
      const int rr = l15 & 3;
      alph[qs] = (rr == 0) ? a0 : (rr == 1) ? a1 : (rr == 2) ? a2 : a3;
    }
#pragma unroll
    for (int qs = 0; qs < 2; ++qs)
#pragma unroll
      for (int mt = 0; mt < 4; ++mt) acc[qs][mt] *= alph[qs];

    // ---- O^T += V^T @ P (A = Vt frags shared across qs; P frags hoisted)
    bf16x8 ph[2][2], pl[2][2];
#pragma unroll
    for (int qs = 0; qs < 2; ++qs)
#pragma unroll
      for (int ks = 0; ks < 2; ++ks) {
        const int prow = w * 32 + qs * 16 + l15;
        const int offp = prow * 64 + (((quad + 4 * ks) ^ (prow & 7)) << 3);
        ph[qs][ks] = ldfrag(&Ps_h[offp]);
        pl[qs][ks] = ldfrag(&Ps_l[offp]);
      }
#pragma unroll
    for (int mt = 0; mt < 4; ++mt) {
#pragma unroll
      for (int ks = 0; ks < 2; ++ks) {
        const int drow = mt * 16 + l15;
        const int offv = drow * 64 + (((quad + 4 * ks) ^ (drow & 7)) << 3);
        const bf16x8 vh = ldfrag(&Vt_h[offv]);
        const bf16x8 vl = ldfrag(&Vt_l[offv]);
#pragma unroll
        for (int qs = 0; qs < 2; ++qs) {
          acc[qs][mt] = MFMA16(vh, ph[qs][ks], acc[qs][mt]);
          acc[qs][mt] = MFMA16(vh, pl[qs][ks], acc[qs][mt]);
          acc[qs][mt] = MFMA16(vl, ph[qs][ks], acc[qs][mt]);
        }
      }
    }
  }

  // ---- epilogue: divide by l (shuffle broadcast), write bf16 O
#pragma unroll
  for (int qs = 0; qs < 2; ++qs) {
    const int src = (l15 >> 2) << 4;
    const float a0 = __shfl(lsum[qs][0], src, 64);
    const float a1 = __shfl(lsum[qs][1], src, 64);
    const float a2 = __shfl(lsum[qs][2], src, 64);
    const float a3 = __shfl(lsum[qs][3], src, 64);
    const int rr = l15 & 3;
    const float lq = (rr == 0) ? a0 : (rr == 1) ? a1 : (rr == 2) ? a2 : a3;
    const float inv = 1.0f / lq;
    const size_t obase =
        (size_t)(b * SEQ + q0 + w * 32 + qs * 16 + l15) * DM + h * 64;
#pragma unroll
    for (int mt = 0; mt < 4; ++mt) {
      u16x4 ov;
#pragma unroll
      for (int r = 0; r < 4; ++r) ov[r] = f2bf(acc[qs][mt][r] * inv);
      *(u16x4*)&ohi[obase + mt * 16 + quad * 4] = ov;
    }
  }
}

// ---------------------------------------------------------------------------
// Launch
// ---------------------------------------------------------------------------
extern "C" void kernel_launch(void* const* d_in, const int* in_sizes, int n_in,
                              void* d_out, int out_size, void* d_ws, size_t ws_size,
                              hipStream_t stream) {
  const float* x    = (const float*)d_in[0];
  const float* Wq   = (const float*)d_in[1];
  const float* Wk   = (const float*)d_in[2];
  const float* Wv   = (const float*)d_in[3];
  const float* Wo   = (const float*)d_in[4];
  const float* qn_w = (const float*)d_in[5];
  const float* kn_w = (const float*)d_in[6];
  const float* Mk   = (const float*)d_in[7];
  const float* Mtk  = (const float*)d_in[8];
  const float* Ck   = (const float*)d_in[9];
  const float* Mv   = (const float*)d_in[10];
  const float* Mtv  = (const float*)d_in[11];
  const float* Cv   = (const float*)d_in[12];
  float* out = (float*)d_out;

  const size_t MBb = 1024ull * 1024ull;
  const size_t SEG = (size_t)DM * DM;  // 4 Mi elements
  char* w = (char*)d_ws;
  float* qb = (float*)(w + 0 * MBb);        // 16 MB each
  float* kb = (float*)(w + 16 * MBb);
  float* vb = (float*)(w + 32 * MBb);
  unsigned short* xhi     = (unsigned short*)(w + 48 * MBb);  // 8 MB each
  unsigned short* xlo     = (unsigned short*)(w + 56 * MBb);
  unsigned short* wcat_hi = (unsigned short*)(w + 64 * MBb);  // 24 MB [6144][2048]
  unsigned short* wcat_lo = (unsigned short*)(w + 88 * MBb);  // 24 MB
  unsigned short* wot     = (unsigned short*)(w + 112 * MBb); // 8 MB
  // Reuse (stream-ordered death):
  unsigned short* q_hi  = wcat_hi;            // seg0 dead after qkv gemm
  unsigned short* k_hi  = wcat_hi + SEG;
  unsigned short* k_lo  = wcat_hi + 2 * SEG;
  unsigned short* q_lo  = wcat_lo;
  unsigned short* vt_hi = wcat_lo + SEG;
  unsigned short* vt_lo = wcat_lo + 2 * SEG;
  unsigned short* o_hi  = xhi;                // x dead after qkv gemm
  float* opart = (float*)(w + 0 * MBb);       // 32 MB; qb/kb dead by out-GEMM

  const int n8 = (NROWS * DM) / 8;

  split_convert_kernel<<<n8 / 256, 256, 0, stream>>>(x, xhi, xlo, n8);
  transpose_split_batch_kernel<<<dim3(DM / 64, DM / 64, 4), 256, 0, stream>>>(
      Wq, Wk, Wv, Wo,
      wcat_hi, wcat_hi + SEG, wcat_lo + SEG, wcat_hi + 2 * SEG, wcat_lo + 2 * SEG, wot);

  qkv_gemm_kernel<<<dim3(3 * DM / 128, NROWS / 128), 256, 0, stream>>>(
      xhi, xlo, wcat_hi, wcat_lo, qb, kb, vb);

  rmsnorm_kernel<<<NROWS, 256, 0, stream>>>(kb, kn_w);
  rmsnorm_split_kernel<<<NROWS, 256, 0, stream>>>(qb, qn_w, q_hi, q_lo, 0.125f);

  quant_kernel<true ><<<NVEC / 256, 256, 0, stream>>>(kb, Mk, Mtk, Ck, k_hi, k_lo);
  quant_kernel<false><<<NVEC / 256, 256, 0, stream>>>(vb, Mv, Mtv, Cv, nullptr, nullptr);
  vt_split_kernel<<<dim3(SEQ / 64, BATCH * HEADS), 256, 0, stream>>>(vb, vt_hi, vt_lo);

  attn_mfma_kernel<<<dim3(SEQ / 128, BATCH * HEADS), 256, 0, stream>>>(
      q_hi, q_lo, k_hi, k_lo, vt_hi, vt_lo, o_hi);

  gemm_out_splitk_kernel<<<dim3(DM / 128, NROWS / 128, 2), 256, 0, stream>>>(
      o_hi, wot, opart);
  add2_f4_kernel<<<(NROWS * DM / 4 + 255) / 256, 256, 0, stream>>>(
      opart, opart + (size_t)NROWS * DM, out, NROWS * DM / 4);
}

// Round 7
// 449.926 us; speedup vs baseline: 1.1287x; 1.1287x over previous
//
#include <hip/hip_runtime.h>
#include <hip/hip_bf16.h>
#include <math.h>

// Problem constants (fixed by the reference)
#define HEADS 32
#define DIM_HEAD 64
#define DM 2048          // HEADS * DIM_HEAD
#define BATCH 2
#define SEQ 1024
#define NROWS (BATCH * SEQ)      // 2048 rows of DM
#define NVEC (NROWS * HEADS)     // 65536 per-head vectors
#define N_GROUPS 22
#define N_LEVELS 8
#define EPS_NORM 1e-8f
#define EPS_RMS 1e-6f

typedef float f32x4 __attribute__((ext_vector_type(4)));
typedef __bf16 bf16x8 __attribute__((ext_vector_type(8)));
typedef unsigned short u16x8 __attribute__((ext_vector_type(8)));
typedef unsigned short u16x4 __attribute__((ext_vector_type(4)));

__device__ __forceinline__ unsigned short f2bf(float x) {
  union { float f; unsigned u; } v; v.f = x;
  unsigned r = v.u + 0x7fffu + ((v.u >> 16) & 1u);  // RTN-even
  return (unsigned short)(r >> 16);
}
__device__ __forceinline__ float bf2f(unsigned short h) {
  union { unsigned u; float f; } v; v.u = ((unsigned)h) << 16;
  return v.f;
}
__device__ __forceinline__ bf16x8 ldfrag(const unsigned short* p) {
  return __builtin_bit_cast(bf16x8, *(const u16x8*)p);
}
#define MFMA16(a, b, c) __builtin_amdgcn_mfma_f32_16x16x32_bf16((a), (b), (c), 0, 0, 0)

__device__ __forceinline__ void stage16(const unsigned short* g, unsigned short* lds) {
  __builtin_amdgcn_global_load_lds(
      (const __attribute__((address_space(1))) unsigned int*)g,
      (__attribute__((address_space(3))) unsigned int*)lds, 16, 0, 0);
}

// ---------------------------------------------------------------------------
// fp32 -> bf16 hi/lo split (lo optional), 8 elements/thread
// ---------------------------------------------------------------------------
__global__ __launch_bounds__(256) void split_convert_kernel(
    const float* __restrict__ X, unsigned short* __restrict__ hi,
    unsigned short* __restrict__ lo, int n8) {
  const int i = blockIdx.x * 256 + threadIdx.x;
  if (i >= n8) return;
  const float4 a = ((const float4*)X)[2 * i];
  const float4 b = ((const float4*)X)[2 * i + 1];
  const float v[8] = {a.x, a.y, a.z, a.w, b.x, b.y, b.z, b.w};
  u16x8 h, l;
#pragma unroll
  for (int j = 0; j < 8; ++j) {
    const unsigned short hh = f2bf(v[j]);
    h[j] = hh;
    l[j] = f2bf(v[j] - bf2f(hh));
  }
  ((u16x8*)hi)[i] = h;
  if (lo) ((u16x8*)lo)[i] = l;
}

// ---------------------------------------------------------------------------
// Batched weight transpose+split: W [K][M] fp32 -> T [M][K] bf16 hi(/lo).
// grid (M/64, K/64, 4): z selects {Wq, Wk, Wv, Wo}.
// ---------------------------------------------------------------------------
__global__ __launch_bounds__(256) void transpose_split_batch_kernel(
    const float* __restrict__ W0, const float* __restrict__ W1,
    const float* __restrict__ W2, const float* __restrict__ W3,
    unsigned short* __restrict__ T0h, unsigned short* __restrict__ T1h,
    unsigned short* __restrict__ T1l, unsigned short* __restrict__ T2h,
    unsigned short* __restrict__ T2l, unsigned short* __restrict__ T3h) {
  const int z = blockIdx.z;
  const float* W = (z == 0) ? W0 : (z == 1) ? W1 : (z == 2) ? W2 : W3;
  unsigned short* Th = (z == 0) ? T0h : (z == 1) ? T1h : (z == 2) ? T2h : T3h;
  unsigned short* Tl = (z == 1) ? T1l : (z == 2) ? T2l : nullptr;

  __shared__ float S[64][65];
  const int t = threadIdx.x;
  const int tk = blockIdx.y * 64, tm = blockIdx.x * 64;
  {
    const int r = t >> 2, cs = (t & 3) * 16;
    const float* src = W + (size_t)(tk + r) * DM + tm + cs;
#pragma unroll
    for (int j = 0; j < 16; j += 4) {
      float4 v = *(const float4*)(src + j);
      S[r][cs + j] = v.x; S[r][cs + j + 1] = v.y;
      S[r][cs + j + 2] = v.z; S[r][cs + j + 3] = v.w;
    }
  }
  __syncthreads();
  const int m = t >> 2, ks = (t & 3) * 16;
  u16x8 h0, h1, l0, l1;
#pragma unroll
  for (int j = 0; j < 8; ++j) {
    const float v = S[ks + j][m];
    const unsigned short hh = f2bf(v);
    h0[j] = hh; l0[j] = f2bf(v - bf2f(hh));
  }
#pragma unroll
  for (int j = 0; j < 8; ++j) {
    const float v = S[ks + 8 + j][m];
    const unsigned short hh = f2bf(v);
    h1[j] = hh; l1[j] = f2bf(v - bf2f(hh));
  }
  const size_t o = (size_t)(tm + m) * DM + tk + ks;
  *(u16x8*)&Th[o] = h0; *(u16x8*)&Th[o + 8] = h1;
  if (Tl) { *(u16x8*)&Tl[o] = l0; *(u16x8*)&Tl[o + 8] = l1; }
}

// ---------------------------------------------------------------------------
// Fused QKV GEMM: A[N=2048][K=2048] @ Bcat[M=6144][K]^T.
// Segments: 0..2047 Wq^T (plain), 2048..4095 Wk^T, 4096..6143 Wv^T (split).
// ---------------------------------------------------------------------------
__global__ __launch_bounds__(256) void qkv_gemm_kernel(
    const unsigned short* __restrict__ Ahi, const unsigned short* __restrict__ Alo,
    const unsigned short* __restrict__ Bhi, const unsigned short* __restrict__ Blo,
    float* __restrict__ q, float* __restrict__ k, float* __restrict__ v) {
  __shared__ unsigned short lAhi[128 * 32];
  __shared__ unsigned short lBhi[128 * 32];
  __shared__ unsigned short lAlo[128 * 32];
  __shared__ unsigned short lBlo[128 * 32];

  const int t = threadIdx.x;
  const int lane = t & 63, wave = t >> 6;
  const int wr = wave >> 1, wc = wave & 1;
  const int gm0 = blockIdx.y * 128;
  const int gnc = blockIdx.x * 128;
  const int seg = gnc >> 11;
  const bool split = (seg != 0);
  const int lrsub = lane >> 2;
  const int lcsub = lane & 3;

  f32x4 acc[4][4] = {};

  for (int kt = 0; kt < DM; kt += 32) {
    __syncthreads();
#pragma unroll
    for (int rg = wave; rg < 8; rg += 4) {
      const int lrow = rg * 16 + lrsub;
      const int c = lcsub ^ ((lrow >> 1) & 3);
      const size_t goffA = (size_t)(gm0 + lrow) * DM + kt + c * 8;
      const size_t goffB = (size_t)(gnc + lrow) * DM + kt + c * 8;
      stage16(Ahi + goffA, lAhi + rg * 512);
      stage16(Bhi + goffB, lBhi + rg * 512);
      if (split) {
        stage16(Alo + goffA, lAlo + rg * 512);
        stage16(Blo + goffB, lBlo + rg * 512);
      }
    }
    __syncthreads();

    bf16x8 ah[4], bh[4], al[4], bl[4];
#pragma unroll
    for (int i = 0; i < 4; ++i) {
      const int mrow = wr * 64 + i * 16 + (lane & 15);
      const int offa = mrow * 32 + (((lane >> 4) ^ ((mrow >> 1) & 3)) << 3);
      ah[i] = ldfrag(&lAhi[offa]);
      const int nrow = wc * 64 + i * 16 + (lane & 15);
      const int offb = nrow * 32 + (((lane >> 4) ^ ((nrow >> 1) & 3)) << 3);
      bh[i] = ldfrag(&lBhi[offb]);
      if (split) {
        al[i] = ldfrag(&lAlo[offa]);
        bl[i] = ldfrag(&lBlo[offb]);
      }
    }
#pragma unroll
    for (int i = 0; i < 4; ++i)
#pragma unroll
      for (int j = 0; j < 4; ++j) {
        acc[i][j] = MFMA16(ah[i], bh[j], acc[i][j]);
        if (split) {
          acc[i][j] = MFMA16(ah[i], bl[j], acc[i][j]);
          acc[i][j] = MFMA16(al[i], bh[j], acc[i][j]);
        }
      }
  }

  float* C = (seg == 0) ? q : (seg == 1) ? k : v;
  const int gn0 = gnc & 2047;
#pragma unroll
  for (int i = 0; i < 4; ++i) {
    const int row = gm0 + wr * 64 + i * 16 + ((lane >> 4) << 2);
#pragma unroll
    for (int j = 0; j < 4; ++j) {
      const int col = gn0 + wc * 64 + j * 16 + (lane & 15);
#pragma unroll
      for (int r = 0; r < 4; ++r)
        C[(size_t)(row + r) * DM + col] = acc[i][j][r];
    }
  }
}

// ---------------------------------------------------------------------------
// Output projection, split-K=2 (plain bf16), partials into Cpart.
// ---------------------------------------------------------------------------
__global__ __launch_bounds__(256) void gemm_out_splitk_kernel(
    const unsigned short* __restrict__ Ahi, const unsigned short* __restrict__ Bt,
    float* __restrict__ Cpart) {
  __shared__ unsigned short lAhi[128 * 32];
  __shared__ unsigned short lBhi[128 * 32];

  const int t = threadIdx.x;
  const int lane = t & 63, wave = t >> 6;
  const int wr = wave >> 1, wc = wave & 1;
  const int gm0 = blockIdx.y * 128, gn0 = blockIdx.x * 128;
  const int z = blockIdx.z;
  const int k0 = z * (DM / 2);
  const int lrsub = lane >> 2;
  const int lcsub = lane & 3;

  f32x4 acc[4][4] = {};

  for (int kt = k0; kt < k0 + DM / 2; kt += 32) {
    __syncthreads();
#pragma unroll
    for (int rg = wave; rg < 8; rg += 4) {
      const int lrow = rg * 16 + lrsub;
      const int c = lcsub ^ ((lrow >> 1) & 3);
      stage16(Ahi + (size_t)(gm0 + lrow) * DM + kt + c * 8, lAhi + rg * 512);
      stage16(Bt + (size_t)(gn0 + lrow) * DM + kt + c * 8, lBhi + rg * 512);
    }
    __syncthreads();

    bf16x8 ah[4], bh[4];
#pragma unroll
    for (int i = 0; i < 4; ++i) {
      const int mrow = wr * 64 + i * 16 + (lane & 15);
      ah[i] = ldfrag(&lAhi[mrow * 32 + (((lane >> 4) ^ ((mrow >> 1) & 3)) << 3)]);
      const int nrow = wc * 64 + i * 16 + (lane & 15);
      bh[i] = ldfrag(&lBhi[nrow * 32 + (((lane >> 4) ^ ((nrow >> 1) & 3)) << 3)]);
    }
#pragma unroll
    for (int i = 0; i < 4; ++i)
#pragma unroll
      for (int j = 0; j < 4; ++j)
        acc[i][j] = MFMA16(ah[i], bh[j], acc[i][j]);
  }

  float* C = Cpart + (size_t)z * NROWS * DM;
#pragma unroll
  for (int i = 0; i < 4; ++i) {
    const int row = gm0 + wr * 64 + i * 16 + ((lane >> 4) << 2);
#pragma unroll
    for (int j = 0; j < 4; ++j) {
      const int col = gn0 + wc * 64 + j * 16 + (lane & 15);
#pragma unroll
      for (int r = 0; r < 4; ++r)
        C[(size_t)(row + r) * DM + col] = acc[i][j][r];
    }
  }
}

__global__ __launch_bounds__(256) void add2_f4_kernel(
    const float* __restrict__ a, const float* __restrict__ b,
    float* __restrict__ o, int n4) {
  const int i = blockIdx.x * 256 + threadIdx.x;
  if (i >= n4) return;
  const float4 x = ((const float4*)a)[i];
  const float4 y = ((const float4*)b)[i];
  ((float4*)o)[i] = make_float4(x.x + y.x, x.y + y.y, x.z + y.z, x.w + y.w);
}

// ---------------------------------------------------------------------------
// Wave reductions
// ---------------------------------------------------------------------------
__device__ __forceinline__ float wave_sum(float x) {
#pragma unroll
  for (int o = 32; o > 0; o >>= 1) x += __shfl_xor(x, o, 64);
  return x;
}

// ---------------------------------------------------------------------------
// RMSNorm in place (fp32), one block per row.  (k path)
// ---------------------------------------------------------------------------
__global__ __launch_bounds__(256) void rmsnorm_kernel(
    float* __restrict__ y, const float* __restrict__ w) {
  __shared__ float rbuf[4];
  const int row = blockIdx.x;
  float* p = y + (size_t)row * DM;
  const int t = threadIdx.x;
  const int wave = t >> 6, lane = t & 63;

  float ss = 0.f;
#pragma unroll
  for (int c = t; c < DM; c += 256) { float v = p[c]; ss += v * v; }
  ss = wave_sum(ss);
  if (lane == 0) rbuf[wave] = ss;
  __syncthreads();
  ss = rbuf[0] + rbuf[1] + rbuf[2] + rbuf[3];
  const float scale = rsqrtf(ss * (1.0f / DM) + EPS_RMS);
#pragma unroll
  for (int c = t; c < DM; c += 256) p[c] = p[c] * scale * w[c];
}

// ---------------------------------------------------------------------------
// RMSNorm -> bf16 hi/lo with extra post-scale (q path: folds 1/8)
// ---------------------------------------------------------------------------
__global__ __launch_bounds__(256) void rmsnorm_split_kernel(
    const float* __restrict__ y, const float* __restrict__ w,
    unsigned short* __restrict__ hi, unsigned short* __restrict__ lo,
    float post) {
  __shared__ float rbuf[4];
  const int row = blockIdx.x;
  const float* p = y + (size_t)row * DM;
  const int t = threadIdx.x;
  const int wave = t >> 6, lane = t & 63;

  const int c0 = t * 8;
  float4 a = *(const float4*)(p + c0);
  float4 b = *(const float4*)(p + c0 + 4);
  float v[8] = {a.x, a.y, a.z, a.w, b.x, b.y, b.z, b.w};
  float ss = 0.f;
#pragma unroll
  for (int j = 0; j < 8; ++j) ss += v[j] * v[j];
  ss = wave_sum(ss);
  if (lane == 0) rbuf[wave] = ss;
  __syncthreads();
  ss = rbuf[0] + rbuf[1] + rbuf[2] + rbuf[3];
  const float scale = rsqrtf(ss * (1.0f / DM) + EPS_RMS) * post;

  u16x8 hv, lv;
#pragma unroll
  for (int j = 0; j < 8; ++j) {
    const float val = v[j] * scale * w[c0 + j];
    const unsigned short hh = f2bf(val);
    hv[j] = hh; lv[j] = f2bf(val - bf2f(hh));
  }
  *(u16x8*)&hi[(size_t)row * DM + c0] = hv;
  *(u16x8*)&lo[(size_t)row * DM + c0] = lv;
}

// ---------------------------------------------------------------------------
// RotorQuant roundtrip. WRITE_BF: emit bf16 hi/lo; else fp32 in place.
// ---------------------------------------------------------------------------
__device__ __forceinline__ float qnearest(float v, const float* __restrict__ C) {
  float best = C[0];
  float bd = fabsf(v - C[0]);
#pragma unroll
  for (int i = 1; i < N_LEVELS; ++i) {
    float d = fabsf(v - C[i]);
    if (d < bd) { bd = d; best = C[i]; }
  }
  return best;
}

template <bool WRITE_BF>
__global__ __launch_bounds__(256) void quant_kernel(
    float* __restrict__ kv, const float* __restrict__ M,
    const float* __restrict__ Mt, const float* __restrict__ C,
    unsigned short* __restrict__ hi, unsigned short* __restrict__ lo) {
  const int vec = blockIdx.x * blockDim.x + threadIdx.x;
  if (vec >= NVEC) return;
  float* p = kv + (size_t)vec * DIM_HEAD;

  float h[66];
  float ss = 0.f;
#pragma unroll
  for (int d = 0; d < DIM_HEAD; ++d) { h[d] = p[d]; ss += h[d] * h[d]; }
  float norm = fmaxf(sqrtf(ss), EPS_NORM);
  const float inv = 1.0f / norm;
#pragma unroll
  for (int d = 0; d < DIM_HEAD; ++d) h[d] *= inv;
  h[64] = 0.f; h[65] = 0.f;

#pragma unroll
  for (int g = 0; g < N_GROUPS; ++g) {
    const float* Mg  = M  + g * 9;
    const float* Mtg = Mt + g * 9;
    const float a0 = h[3 * g + 0], a1 = h[3 * g + 1], a2 = h[3 * g + 2];
    const float r0 = a0 * Mg[0] + a1 * Mg[3] + a2 * Mg[6];
    const float r1 = a0 * Mg[1] + a1 * Mg[4] + a2 * Mg[7];
    const float r2 = a0 * Mg[2] + a1 * Mg[5] + a2 * Mg[8];
    const float d0 = qnearest(r0, C);
    const float d1 = qnearest(r1, C);
    const float d2 = qnearest(r2, C);
    h[3 * g + 0] = d0 * Mtg[0] + d1 * Mtg[3] + d2 * Mtg[6];
    h[3 * g + 1] = d0 * Mtg[1] + d1 * Mtg[4] + d2 * Mtg[7];
    h[3 * g + 2] = d0 * Mtg[2] + d1 * Mtg[5] + d2 * Mtg[8];
  }
  if (WRITE_BF) {
#pragma unroll
    for (int g8 = 0; g8 < 8; ++g8) {
      u16x8 hv, lv;
#pragma unroll
      for (int j = 0; j < 8; ++j) {
        const float val = h[g8 * 8 + j] * norm;
        const unsigned short hh = f2bf(val);
        hv[j] = hh; lv[j] = f2bf(val - bf2f(hh));
      }
      *(u16x8*)&hi[(size_t)vec * DIM_HEAD + g8 * 8] = hv;
      *(u16x8*)&lo[(size_t)vec * DIM_HEAD + g8 * 8] = lv;
    }
  } else {
#pragma unroll
    for (int d = 0; d < DIM_HEAD; ++d) p[d] = h[d] * norm;
  }
}

// ---------------------------------------------------------------------------
// Per-head V transpose + split: v[b][s][h*64+d] fp32 -> vt[(bh*64+d)][s] hi/lo
// ---------------------------------------------------------------------------
__global__ __launch_bounds__(256) void vt_split_kernel(
    const float* __restrict__ v, unsigned short* __restrict__ hi,
    unsigned short* __restrict__ lo) {
  __shared__ float T[64][65];
  const int s0 = blockIdx.x * 64;
  const int bh = blockIdx.y;
  const int b = bh >> 5, h = bh & 31;
  const int t = threadIdx.x;
  {
    const int sr = t >> 2, dseg = (t & 3) * 16;
    const float* src = v + ((size_t)(b * SEQ + s0 + sr) * DM + h * 64 + dseg);
#pragma unroll
    for (int j = 0; j < 16; j += 4) {
      float4 a = *(const float4*)(src + j);
      T[sr][dseg + j] = a.x; T[sr][dseg + j + 1] = a.y;
      T[sr][dseg + j + 2] = a.z; T[sr][dseg + j + 3] = a.w;
    }
  }
  __syncthreads();
  const int d = t >> 2, sseg = (t & 3) * 16;
  u16x8 h0, h1, l0, l1;
#pragma unroll
  for (int j = 0; j < 8; ++j) {
    const float val = T[sseg + j][d];
    const unsigned short hh = f2bf(val);
    h0[j] = hh; l0[j] = f2bf(val - bf2f(hh));
  }
#pragma unroll
  for (int j = 0; j < 8; ++j) {
    const float val = T[sseg + 8 + j][d];
    const unsigned short hh = f2bf(val);
    h1[j] = hh; l1[j] = f2bf(val - bf2f(hh));
  }
  const size_t o = (size_t)(bh * 64 + d) * SEQ + s0 + sseg;
  *(u16x8*)&hi[o] = h0; *(u16x8*)&hi[o + 8] = h1;
  *(u16x8*)&lo[o] = l0; *(u16x8*)&lo[o + 8] = l1;
}

// ---------------------------------------------------------------------------
// MFMA flash attention, split-bf16. Block = (b,h,64 q rows), 256 threads.
// R5 structure (3 blocks/CU) + Q frags direct from global + P packed as
// hi|lo u32 in one LDS array (halves P write ops) + XCD-locality grid
// (blockIdx.x = bh so same-bh blocks share an XCD's L2).
// LDS = 48 KB exactly.
// ---------------------------------------------------------------------------
__global__ __launch_bounds__(256) void attn_mfma_kernel(
    const unsigned short* __restrict__ qhi, const unsigned short* __restrict__ qlo,
    const unsigned short* __restrict__ khi, const unsigned short* __restrict__ klo,
    const unsigned short* __restrict__ vthi, const unsigned short* __restrict__ vtlo,
    unsigned short* __restrict__ ohi) {
  __shared__ unsigned short Ks_h[4096], Ks_l[4096];   // [64 key][64 d]
  __shared__ unsigned short Vt_h[4096], Vt_l[4096];   // [64 d][64 s]
  __shared__ unsigned int   Ps[4096];                 // [64 q][64 key] (hi<<16|lo)

  const int bh = blockIdx.x;        // 0..63  (XCD = bh % 8 -> L2 locality)
  const int qt = blockIdx.y;        // 0..15
  const int h = bh & 31, b = bh >> 5;
  const int q0 = qt * 64;
  const int t = threadIdx.x, lane = t & 63, w = t >> 6;
  const int quad = lane >> 4, l15 = lane & 15;
  const int srow = lane >> 3, schunk = lane & 7;

  // wave w stages rows [w*16, w*16+16) of a [64][64 u16] tile
  auto stage = [&](const unsigned short* g, int stride, unsigned short* arr) {
#pragma unroll
    for (int it = 0; it < 2; ++it) {
      const int r = w * 16 + it * 8 + srow;
      const int c = schunk ^ (r & 7);
      stage16(g + (size_t)r * stride + c * 8, arr + (w * 16 + it * 8) * 64);
    }
  };

  // ---- Q frags directly from global (A-frag: row = w*16+l15, k = ks*32+quad*8)
  bf16x8 qh[2], ql[2];
  {
    const size_t qrow = (size_t)(b * SEQ + q0 + w * 16 + l15) * DM + h * 64;
#pragma unroll
    for (int ks = 0; ks < 2; ++ks) {
      qh[ks] = ldfrag(&qhi[qrow + ks * 32 + quad * 8]);
      ql[ks] = ldfrag(&qlo[qrow + ks * 32 + quad * 8]);
    }
  }

  f32x4 acc[4] = {};                       // O^T: rows d = mt*16+quad*4+reg, col q = w*16+l15
  float m_prev[4] = {-INFINITY, -INFINITY, -INFINITY, -INFINITY};
  float lsum[4] = {0.f, 0.f, 0.f, 0.f};

  const unsigned short* gkh = khi + ((size_t)(b * SEQ) * DM + h * 64);
  const unsigned short* gkl = klo + ((size_t)(b * SEQ) * DM + h * 64);
  const unsigned short* gvh = vthi + (size_t)(bh * 64) * SEQ;
  const unsigned short* gvl = vtlo + (size_t)(bh * 64) * SEQ;

  for (int kt = 0; kt < SEQ; kt += 64) {
    __syncthreads();                       // prev iter's K/Vt frag reads done
    stage(gkh + (size_t)kt * DM, DM, Ks_h);
    stage(gkl + (size_t)kt * DM, DM, Ks_l);
    stage(gvh + kt, SEQ, Vt_h);
    stage(gvl + kt, SEQ, Vt_l);
    __syncthreads();                       // staging drained

    // ---- S = (Q/8) @ K^T, split: Qh*Kh + Qh*Kl + Ql*Kh
    f32x4 s[4] = {};
#pragma unroll
    for (int nt = 0; nt < 4; ++nt) {
#pragma unroll
      for (int ks = 0; ks < 2; ++ks) {
        const int row = nt * 16 + l15;
        const int off = row * 64 + (((quad + 4 * ks) ^ (row & 7)) << 3);
        const bf16x8 kh = ldfrag(&Ks_h[off]);
        const bf16x8 kl = ldfrag(&Ks_l[off]);
        s[nt] = MFMA16(qh[ks], kh, s[nt]);
        s[nt] = MFMA16(qh[ks], kl, s[nt]);
        s[nt] = MFMA16(ql[ks], kh, s[nt]);
      }
    }

    // ---- online softmax per q row (C-layout row = quad*4 + r)
    float asave[4];
#pragma unroll
    for (int r = 0; r < 4; ++r) {
      float mx = fmaxf(fmaxf(s[0][r], s[1][r]), fmaxf(s[2][r], s[3][r]));
#pragma unroll
      for (int off = 1; off < 16; off <<= 1) mx = fmaxf(mx, __shfl_xor(mx, off, 64));
      const float mn = fmaxf(m_prev[r], mx);
      const float al = __expf(m_prev[r] - mn);
      float rs = 0.f;
#pragma unroll
      for (int nt = 0; nt < 4; ++nt) {
        const float e = __expf(s[nt][r] - mn);
        s[nt][r] = e; rs += e;
      }
#pragma unroll
      for (int off = 1; off < 16; off <<= 1) rs += __shfl_xor(rs, off, 64);
      lsum[r] = lsum[r] * al + rs;
      m_prev[r] = mn;
      asave[r] = al;
      // P row write (wave-private rows): packed hi|lo u32, one op per key
      const int prow = w * 16 + quad * 4 + r;
#pragma unroll
      for (int nt = 0; nt < 4; ++nt) {
        const int kk = nt * 16 + l15;
        const unsigned short hh = f2bf(s[nt][r]);
        const unsigned short ll = f2bf(s[nt][r] - bf2f(hh));
        Ps[prow * 64 + (kk ^ ((prow & 7) << 3))] =
            ((unsigned)hh << 16) | (unsigned)ll;
      }
    }

    // ---- broadcast alpha to O^T lanes (col q = l15) via shuffle
    {
      const int src = (l15 >> 2) << 4;
      const float a0 = __shfl(asave[0], src, 64);
      const float a1 = __shfl(asave[1], src, 64);
      const float a2 = __shfl(asave[2], src, 64);
      const float a3 = __shfl(asave[3], src, 64);
      const int rr = l15 & 3;
      const float alph = (rr == 0) ? a0 : (rr == 1) ? a1 : (rr == 2) ? a2 : a3;
#pragma unroll
      for (int mt = 0; mt < 4; ++mt) acc[mt] *= alph;
    }

    // ---- unpack P frags (B-frag: n = l15 = q-col... rows q, k = key)
    bf16x8 ph[2], pl[2];
#pragma unroll
    for (int ks = 0; ks < 2; ++ks) {
      const int prow = w * 16 + l15;
      const unsigned int* pp =
          &Ps[prow * 64 + ((ks * 32 + quad * 8) ^ ((prow & 7) << 3))];
      const uint4 pa = *(const uint4*)pp;
      const uint4 pb = *(const uint4*)(pp + 4);
      u16x8 hv, lv;
      const unsigned int pw[8] = {pa.x, pa.y, pa.z, pa.w, pb.x, pb.y, pb.z, pb.w};
#pragma unroll
      for (int j = 0; j < 8; ++j) {
        hv[j] = (unsigned short)(pw[j] >> 16);
        lv[j] = (unsigned short)(pw[j] & 0xffffu);
      }
      ph[ks] = __builtin_bit_cast(bf16x8, hv);
      pl[ks] = __builtin_bit_cast(bf16x8, lv);
    }

    // ---- O^T += V^T @ P  (A = Vt frags, B = P frags)
#pragma unroll
    for (int mt = 0; mt < 4; ++mt) {
#pragma unroll
      for (int ks = 0; ks < 2; ++ks) {
        const int drow = mt * 16 + l15;
        const int offv = drow * 64 + (((quad + 4 * ks) ^ (drow & 7)) << 3);
        const bf16x8 vh = ldfrag(&Vt_h[offv]);
        const bf16x8 vl = ldfrag(&Vt_l[offv]);
        acc[mt] = MFMA16(vh, ph[ks], acc[mt]);
        acc[mt] = MFMA16(vh, pl[ks], acc[mt]);
        acc[mt] = MFMA16(vl, ph[ks], acc[mt]);
      }
    }
  }

  // ---- epilogue: divide by l (shuffle broadcast), write bf16 O
  {
    const int src = (l15 >> 2) << 4;
    const float a0 = __shfl(lsum[0], src, 64);
    const float a1 = __shfl(lsum[1], src, 64);
    const float a2 = __shfl(lsum[2], src, 64);
    const float a3 = __shfl(lsum[3], src, 64);
    const int rr = l15 & 3;
    const float lq = (rr == 0) ? a0 : (rr == 1) ? a1 : (rr == 2) ? a2 : a3;
    const float inv = 1.0f / lq;
    const size_t obase = (size_t)(b * SEQ + q0 + w * 16 + l15) * DM + h * 64;
#pragma unroll
    for (int mt = 0; mt < 4; ++mt) {
      u16x4 ov;
#pragma unroll
      for (int r = 0; r < 4; ++r) ov[r] = f2bf(acc[mt][r] * inv);
      *(u16x4*)&ohi[obase + mt * 16 + quad * 4] = ov;
    }
  }
}

// ---------------------------------------------------------------------------
// Launch
// ---------------------------------------------------------------------------
extern "C" void kernel_launch(void* const* d_in, const int* in_sizes, int n_in,
                              void* d_out, int out_size, void* d_ws, size_t ws_size,
                              hipStream_t stream) {
  const float* x    = (const float*)d_in[0];
  const float* Wq   = (const float*)d_in[1];
  const float* Wk   = (const float*)d_in[2];
  const float* Wv   = (const float*)d_in[3];
  const float* Wo   = (const float*)d_in[4];
  const float* qn_w = (const float*)d_in[5];
  const float* kn_w = (const float*)d_in[6];
  const float* Mk   = (const float*)d_in[7];
  const float* Mtk  = (const float*)d_in[8];
  const float* Ck   = (const float*)d_in[9];
  const float* Mv   = (const float*)d_in[10];
  const float* Mtv  = (const float*)d_in[11];
  const float* Cv   = (const float*)d_in[12];
  float* out = (float*)d_out;

  const size_t MBb = 1024ull * 1024ull;
  const size_t SEG = (size_t)DM * DM;  // 4 Mi elements
  char* w = (char*)d_ws;
  float* qb = (float*)(w + 0 * MBb);        // 16 MB each
  float* kb = (float*)(w + 16 * MBb);
  float* vb = (float*)(w + 32 * MBb);
  unsigned short* xhi     = (unsigned short*)(w + 48 * MBb);  // 8 MB each
  unsigned short* xlo     = (unsigned short*)(w + 56 * MBb);
  unsigned short* wcat_hi = (unsigned short*)(w + 64 * MBb);  // 24 MB [6144][2048]
  unsigned short* wcat_lo = (unsigned short*)(w + 88 * MBb);  // 24 MB
  unsigned short* wot     = (unsigned short*)(w + 112 * MBb); // 8 MB
  // Reuse (stream-ordered death):
  unsigned short* q_hi  = wcat_hi;            // seg0 dead after qkv gemm
  unsigned short* k_hi  = wcat_hi + SEG;
  unsigned short* k_lo  = wcat_hi + 2 * SEG;
  unsigned short* q_lo  = wcat_lo;
  unsigned short* vt_hi = wcat_lo + SEG;
  unsigned short* vt_lo = wcat_lo + 2 * SEG;
  unsigned short* o_hi  = xhi;                // x dead after qkv gemm
  float* opart = (float*)(w + 0 * MBb);       // 32 MB; qb/kb dead by out-GEMM

  const int n8 = (NROWS * DM) / 8;

  split_convert_kernel<<<n8 / 256, 256, 0, stream>>>(x, xhi, xlo, n8);
  transpose_split_batch_kernel<<<dim3(DM / 64, DM / 64, 4), 256, 0, stream>>>(
      Wq, Wk, Wv, Wo,
      wcat_hi, wcat_hi + SEG, wcat_lo + SEG, wcat_hi + 2 * SEG, wcat_lo + 2 * SEG, wot);

  qkv_gemm_kernel<<<dim3(3 * DM / 128, NROWS / 128), 256, 0, stream>>>(
      xhi, xlo, wcat_hi, wcat_lo, qb, kb, vb);

  rmsnorm_kernel<<<NROWS, 256, 0, stream>>>(kb, kn_w);
  rmsnorm_split_kernel<<<NROWS, 256, 0, stream>>>(qb, qn_w, q_hi, q_lo, 0.125f);

  quant_kernel<true ><<<NVEC / 256, 256, 0, stream>>>(kb, Mk, Mtk, Ck, k_hi, k_lo);
  quant_kernel<false><<<NVEC / 256, 256, 0, stream>>>(vb, Mv, Mtv, Cv, nullptr, nullptr);
  vt_split_kernel<<<dim3(SEQ / 64, BATCH * HEADS), 256, 0, stream>>>(vb, vt_hi, vt_lo);

  attn_mfma_kernel<<<dim3(BATCH * HEADS, SEQ / 64), 256, 0, stream>>>(
      q_hi, q_lo, k_hi, k_lo, vt_hi, vt_lo, o_hi);

  gemm_out_splitk_kernel<<<dim3(DM / 128, NROWS / 128, 2), 256, 0, stream>>>(
      o_hi, wot, opart);
  add2_f4_kernel<<<(NROWS * DM / 4 + 255) / 256, 256, 0, stream>>>(
      opart, opart + (size_t)NROWS * DM, out, NROWS * DM / 4);
}